// Round 8
// baseline (91.127 us; speedup 1.0000x reference)
//
#include <hip/hip_runtime.h>
#include <hip/hip_bf16.h>

typedef __attribute__((ext_vector_type(8))) short bf16x8;
typedef __attribute__((ext_vector_type(4))) float f32x4;

__device__ __forceinline__ ushort f2bf(float f) {
    __hip_bfloat16 h = __float2bfloat16(f);
    return __builtin_bit_cast(ushort, h);
}
__device__ __forceinline__ float bflo(unsigned u) { return __uint_as_float(u << 16); }
__device__ __forceinline__ float bfhi(unsigned u) { return __uint_as_float(u & 0xffff0000u); }

__device__ __forceinline__ void unpack8(uint4 r, float* o) {
    o[0] = bflo(r.x); o[1] = bfhi(r.x); o[2] = bflo(r.y); o[3] = bfhi(r.y);
    o[4] = bflo(r.z); o[5] = bfhi(r.z); o[6] = bflo(r.w); o[7] = bfhi(r.w);
}

__device__ __forceinline__ void gload16(const void* g, void* l) {
    __builtin_amdgcn_global_load_lds(
        (const __attribute__((address_space(1))) unsigned*)g,
        (__attribute__((address_space(3))) unsigned*)l,
        16, 0, 0);
}

// ---------------------------------------------------------------------------
// L1: convert w_kv to bf16 AND zero atomic accumulators
// (statacc 1024 | rowsum 2048 | ctx 65536 contiguous at f[0..68608)).
__global__ void cvtw_kernel(const float* __restrict__ w, ushort* __restrict__ o,
                            float* __restrict__ zbase) {
    int i = blockIdx.x * 256 + threadIdx.x;      // 0..131071
    if (i < 68608) zbase[i] = 0.f;
    o[i] = f2bf(w[i]);
}

// ---------------------------------------------------------------------------
// L2 merged: blocks [0,1024): kv = w_kv @ cond (64x64 MFMA tiles, B transposed
//            +converted in LDS staging from fp32 cond);
//            blocks [1024,1536): GroupNorm sums for x, one block per (b,g).
__global__ __launch_bounds__(256) void kvstats_kernel(const ushort* __restrict__ wkv16,
                                                      const float* __restrict__ cond,
                                                      const float* __restrict__ b_kv,
                                                      ushort* __restrict__ kv16,
                                                      const float* __restrict__ x,
                                                      float* __restrict__ statacc) {
    __shared__ ushort lA[64 * 64];
    __shared__ ushort lB[64 * 64];
    __shared__ float ls[4], lss[4];
    int bid = blockIdx.x;
    int t = threadIdx.x;
    if (bid < 1024) {
        int nb = bid & 15, ob = (bid >> 4) & 3, b = bid >> 6;
        int col0 = nb * 64, row0 = ob * 64;
        int l = t & 63, wid = t >> 6;
        int wr = wid >> 1, wc = wid & 1;
        int lr = l & 15, lg = l >> 4;
        const ushort* Ab = wkv16 + (size_t)row0 * 512;
        const float* Bb = cond + (size_t)b * 512 * 1024;
        int sp = t & 31, sj = t >> 5;          // c-pair (2sp,2sp+1), n-octet
        f32x4 acc[2][2] = {};
        for (int k0 = 0; k0 < 512; k0 += 64) {
            #pragma unroll
            for (int j = 0; j < 2; ++j) {
                int gi = j * 256 + t;
                int r = gi >> 3, g = (gi & 7) ^ (r & 7);
                gload16(Ab + (size_t)r * 512 + k0 + g * 8, (char*)lA + gi * 16);
            }
            const float* r0 = Bb + (size_t)(k0 + 2 * sp) * 1024 + col0 + sj * 8;
            float4 v0a = *(const float4*)r0;
            float4 v0b = *(const float4*)(r0 + 4);
            float4 v1a = *(const float4*)(r0 + 1024);
            float4 v1b = *(const float4*)(r0 + 1028);
            float c0v[8] = {v0a.x, v0a.y, v0a.z, v0a.w, v0b.x, v0b.y, v0b.z, v0b.w};
            float c1v[8] = {v1a.x, v1a.y, v1a.z, v1a.w, v1b.x, v1b.y, v1b.z, v1b.w};
            #pragma unroll
            for (int w = 0; w < 8; ++w) {
                int n = sj * 8 + w;
                unsigned pk = (unsigned)f2bf(c0v[w]) | ((unsigned)f2bf(c1v[w]) << 16);
                *(unsigned*)((char*)lB + n * 128 + (((sp >> 2) ^ (n & 7)) * 16) + (sp & 3) * 4) = pk;
            }
            __syncthreads();
            #pragma unroll
            for (int ks = 0; ks < 2; ++ks) {
                bf16x8 av[2], bv[2];
                #pragma unroll
                for (int mi = 0; mi < 2; ++mi) {
                    int ar = wr * 32 + mi * 16 + lr;
                    int q = (ks * 4 + lg) ^ (ar & 7);
                    av[mi] = *(const bf16x8*)((const char*)lA + ar * 128 + q * 16);
                }
                #pragma unroll
                for (int ni = 0; ni < 2; ++ni) {
                    int br = wc * 32 + ni * 16 + lr;
                    int q = (ks * 4 + lg) ^ (br & 7);
                    bv[ni] = *(const bf16x8*)((const char*)lB + br * 128 + q * 16);
                }
                #pragma unroll
                for (int mi = 0; mi < 2; ++mi)
                    #pragma unroll
                    for (int ni = 0; ni < 2; ++ni)
                        acc[mi][ni] = __builtin_amdgcn_mfma_f32_16x16x32_bf16(
                            av[mi], bv[ni], acc[mi][ni], 0, 0, 0);
            }
            __syncthreads();
        }
        int orow = row0 + wr * 32, ocol = col0 + wc * 32 + lr;
        #pragma unroll
        for (int mi = 0; mi < 2; ++mi) {
            int rb = orow + mi * 16 + lg * 4;
            float4 b4 = *(const float4*)&b_kv[rb];
            float bvr[4] = {b4.x, b4.y, b4.z, b4.w};
            #pragma unroll
            for (int ni = 0; ni < 2; ++ni) {
                int cc = ocol + ni * 16;
                #pragma unroll
                for (int r = 0; r < 4; ++r)
                    kv16[((size_t)b * 256 + rb + r) * 1024 + cc] = f2bf(acc[mi][ni][r] + bvr[r]);
            }
        }
    } else {
        int bg = bid - 1024;
        const float4* xp = (const float4*)(x + (size_t)bg * 32768);
        float s = 0.f, ss = 0.f;
        for (int i = t; i < 8192; i += 256) {
            float4 v = xp[i];
            s  += v.x + v.y + v.z + v.w;
            ss += v.x*v.x + v.y*v.y + v.z*v.z + v.w*v.w;
        }
        #pragma unroll
        for (int off = 32; off > 0; off >>= 1) {
            s  += __shfl_down(s, off, 64);
            ss += __shfl_down(ss, off, 64);
        }
        int wave = t >> 6;
        if ((t & 63) == 0) { ls[wave] = s; lss[wave] = ss; }
        __syncthreads();
        if (t == 0) {
            statacc[bg * 2]     = ls[0] + ls[1] + ls[2] + ls[3];
            statacc[bg * 2 + 1] = lss[0] + lss[1] + lss[2] + lss[3];
        }
    }
}

// ---------------------------------------------------------------------------
// L3: partial context, UNNORMALIZED: ctx[d,e] += sum_n exp(k[d,n]) v[e,n],
// rowsum[d] += sum_n exp(k[d,n]).  grid (8 nchunks, 64 bh).
__global__ __launch_bounds__(256) void ctx_partial_kernel(const ushort* __restrict__ kv,
                                                          float* __restrict__ rowsum,
                                                          float* __restrict__ ctx) {
    int bh = blockIdx.y, b = bh >> 2, h = bh & 3;
    int n0 = blockIdx.x * 128;
    __shared__ float pl[32][129], vl[32][129];
    int t = threadIdx.x;
    int r = t >> 3, cs = (t & 7) * 16;
    const ushort* kp = kv + ((size_t)b * 256 + h * 32 + r) * 1024 + n0 + cs;
    const ushort* vp = kv + ((size_t)b * 256 + 128 + h * 32 + r) * 1024 + n0 + cs;
    float kvals[16], vvals[16];
    unpack8(((const uint4*)kp)[0], kvals);
    unpack8(((const uint4*)kp)[1], kvals + 8);
    unpack8(((const uint4*)vp)[0], vvals);
    unpack8(((const uint4*)vp)[1], vvals + 8);
    float psum = 0.f;
    #pragma unroll
    for (int i = 0; i < 16; ++i) {
        float e = __expf(kvals[i]);
        pl[r][cs + i] = e;
        vl[r][cs + i] = vvals[i];
        psum += e;
    }
    psum += __shfl_xor(psum, 1, 64);
    psum += __shfl_xor(psum, 2, 64);
    psum += __shfl_xor(psum, 4, 64);
    if ((t & 7) == 0) atomicAdd(&rowsum[bh * 32 + r], psum);
    __syncthreads();
    int d0 = t >> 5, e0 = t & 31;
    float acc[4] = {0.f, 0.f, 0.f, 0.f};
    #pragma unroll 8
    for (int nn = 0; nn < 128; ++nn) {
        float vv = vl[e0][nn];
        #pragma unroll
        for (int i = 0; i < 4; ++i)
            acc[i] += pl[d0 + 8 * i][nn] * vv;
    }
    #pragma unroll
    for (int i = 0; i < 4; ++i)
        atomicAdd(&ctx[((size_t)bh * 32 + d0 + 8 * i) * 32 + e0], acc[i]);
}

// ---------------------------------------------------------------------------
// L4: A-fold: normalize ctx by rowsum, M = w_out@ctx^T in LDS, then
// A16[b,o,c] = bf16(wt*s), biasb[b,o] = sum_c wt*t + M.b_q + b_out
__global__ __launch_bounds__(256) void a_kernel(const float* __restrict__ ctx,
                                                const float* __restrict__ rowsum,
                                                const float* __restrict__ w_out,
                                                const float* __restrict__ w_q,
                                                const float* __restrict__ b_q,
                                                const float* __restrict__ statacc,
                                                const float* __restrict__ gn_w,
                                                const float* __restrict__ gn_b,
                                                const float* __restrict__ b_out,
                                                ushort* __restrict__ A16,
                                                float* __restrict__ biasb) {
    __shared__ float ctxl[4][32][33];
    __shared__ float wol[16][128];
    __shared__ float ml[16][128];
    __shared__ float cbuf[256][17];
    __shared__ float pbuf[16][17];
    int b = blockIdx.x >> 4, ot = (blockIdx.x & 15) << 4;
    int t = threadIdx.x;
    #pragma unroll
    for (int j = 0; j < 16; ++j) {
        int e = t + 256 * j;            // 0..4095
        float inv = 1.f / rowsum[b * 128 + (e >> 5)];
        ctxl[e >> 10][(e >> 5) & 31][e & 31] = ctx[(size_t)b * 4096 + e] * inv;
    }
    #pragma unroll
    for (int j = 0; j < 8; ++j) {
        int e = t + 256 * j;            // 0..2047
        wol[e >> 7][e & 127] = w_out[(ot + (e >> 7)) * 128 + (e & 127)];
    }
    __syncthreads();
    #pragma unroll
    for (int j = 0; j < 8; ++j) {
        int e = t + 256 * j;
        int o = e >> 7, hd = e & 127, h = hd >> 5, d = hd & 31;
        float acc = 0.f;
        #pragma unroll
        for (int ee = 0; ee < 32; ++ee) acc += wol[o][h * 32 + ee] * ctxl[h][d][ee];
        ml[o][hd] = acc;
    }
    __syncthreads();
    int c = t, g = c >> 3;
    float a0 = statacc[(b * 32 + g) * 2], a1 = statacc[(b * 32 + g) * 2 + 1];
    float mu  = a0 * (1.f / 32768.f);
    float var = a1 * (1.f / 32768.f) - mu * mu;
    float sc = rsqrtf(var + 1e-5f) * gn_w[c];
    float tc = gn_b[c] - mu * sc;
    float wt[16];
    #pragma unroll
    for (int o = 0; o < 16; ++o) wt[o] = 0.f;
    for (int hd = 0; hd < 128; ++hd) {
        float wq = w_q[hd * 256 + c];
        #pragma unroll
        for (int o = 0; o < 16; ++o) wt[o] += ml[o][hd] * wq;
    }
    ushort* Abp = A16 + ((size_t)b * 256 + ot) * 256 + c;
    #pragma unroll
    for (int o = 0; o < 16; ++o) {
        Abp[(size_t)o * 256] = f2bf(wt[o] * sc);
        cbuf[c][o] = wt[o] * tc;
    }
    __syncthreads();
    {
        int o = t >> 4, seg = t & 15;
        float p = 0.f;
        #pragma unroll
        for (int i = 0; i < 16; ++i) p += cbuf[seg * 16 + i][o];
        pbuf[o][seg] = p;
    }
    __syncthreads();
    if (t < 16) {
        int o = t;
        float sum = 0.f;
        #pragma unroll
        for (int s2 = 0; s2 < 16; ++s2) sum += pbuf[o][s2];
        float md = 0.f;
        #pragma unroll 8
        for (int hd = 0; hd < 128; ++hd) md += ml[o][hd] * b_q[hd];
        biasb[(size_t)b * 256 + ot + o] = sum + md + b_out[ot + o];
    }
}

// ---------------------------------------------------------------------------
// L5: out = A16 @ x^T + bias.  BM=256 (all o), BN=128, BK=64; 8 waves (4x2).
// B operand read as fp32 rows of x, converted+transposed in LDS staging.
__global__ __launch_bounds__(512) void out_gemm_fused(const ushort* __restrict__ A16,
                                                      const float* __restrict__ x,
                                                      const float* __restrict__ biasb,
                                                      float* __restrict__ out) {
    __shared__ ushort lA[256 * 64];   // 32 KB
    __shared__ ushort lB[128 * 64];   // 16 KB
    int b = blockIdx.y;
    int n0 = blockIdx.x * 128;
    int t = threadIdx.x;
    int l = t & 63, wid = t >> 6;
    int wr = wid >> 1, wc = wid & 1;          // 4 x 2 wave grid
    int lr = l & 15, lg = l >> 4;
    const ushort* Ab = A16 + (size_t)b * 65536;
    const float* xb = x + (size_t)b * 256 * 4096;
    int sp = t & 31, sj = t >> 5;             // c-pair (2sp,2sp+1), n-octet (16)
    f32x4 acc[4][4] = {};
    for (int k0 = 0; k0 < 256; k0 += 64) {
        #pragma unroll
        for (int j = 0; j < 4; ++j) {
            int gi = j * 512 + t;             // 2048 granules
            int r = gi >> 3, g = (gi & 7) ^ (r & 7);
            gload16(Ab + (size_t)r * 256 + k0 + g * 8, (char*)lA + gi * 16);
        }
        const float* r0 = xb + (size_t)(k0 + 2 * sp) * 4096 + n0 + sj * 8;
        float4 v0a = *(const float4*)r0;
        float4 v0b = *(const float4*)(r0 + 4);
        float4 v1a = *(const float4*)(r0 + 4096);
        float4 v1b = *(const float4*)(r0 + 4100);
        float c0v[8] = {v0a.x, v0a.y, v0a.z, v0a.w, v0b.x, v0b.y, v0b.z, v0b.w};
        float c1v[8] = {v1a.x, v1a.y, v1a.z, v1a.w, v1b.x, v1b.y, v1b.z, v1b.w};
        #pragma unroll
        for (int w = 0; w < 8; ++w) {
            int n = sj * 8 + w;
            unsigned pk = (unsigned)f2bf(c0v[w]) | ((unsigned)f2bf(c1v[w]) << 16);
            *(unsigned*)((char*)lB + n * 128 + (((sp >> 2) ^ (n & 7)) * 16) + (sp & 3) * 4) = pk;
        }
        __syncthreads();
        #pragma unroll
        for (int ks = 0; ks < 2; ++ks) {
            bf16x8 av[4], bv[4];
            #pragma unroll
            for (int mi = 0; mi < 4; ++mi) {
                int ar = wr * 64 + mi * 16 + lr;
                int q = (ks * 4 + lg) ^ (ar & 7);
                av[mi] = *(const bf16x8*)((const char*)lA + ar * 128 + q * 16);
            }
            #pragma unroll
            for (int ni = 0; ni < 4; ++ni) {
                int br = wc * 64 + ni * 16 + lr;
                int q = (ks * 4 + lg) ^ (br & 7);
                bv[ni] = *(const bf16x8*)((const char*)lB + br * 128 + q * 16);
            }
            #pragma unroll
            for (int mi = 0; mi < 4; ++mi)
                #pragma unroll
                for (int ni = 0; ni < 4; ++ni)
                    acc[mi][ni] = __builtin_amdgcn_mfma_f32_16x16x32_bf16(
                        av[mi], bv[ni], acc[mi][ni], 0, 0, 0);
        }
        __syncthreads();
    }
    const float* bp = biasb + (size_t)b * 256;
    int orow = wr * 64, ocol = n0 + wc * 64 + lr;
    #pragma unroll
    for (int mi = 0; mi < 4; ++mi) {
        int rb = orow + mi * 16 + lg * 4;
        float4 b4 = *(const float4*)&bp[rb];
        float bvr[4] = {b4.x, b4.y, b4.z, b4.w};
        #pragma unroll
        for (int ni = 0; ni < 4; ++ni) {
            int cc = ocol + ni * 16;
            #pragma unroll
            for (int r = 0; r < 4; ++r)
                out[((size_t)b * 256 + rb + r) * 4096 + cc] = acc[mi][ni][r] + bvr[r];
        }
    }
}

extern "C" void kernel_launch(void* const* d_in, const int* in_sizes, int n_in,
                              void* d_out, int out_size, void* d_ws, size_t ws_size,
                              hipStream_t stream) {
    const float* x     = (const float*)d_in[0];
    const float* cond  = (const float*)d_in[1];
    const float* gn_w  = (const float*)d_in[2];
    const float* gn_b  = (const float*)d_in[3];
    const float* w_q   = (const float*)d_in[4];
    const float* b_q   = (const float*)d_in[5];
    const float* w_kv  = (const float*)d_in[6];
    const float* b_kv  = (const float*)d_in[7];
    const float* w_out = (const float*)d_in[8];
    const float* b_out = (const float*)d_in[9];
    float* out = (float*)d_out;

    float* f       = (float*)d_ws;
    float* statacc = f;                     // 1024 floats
    float* rowsum  = f + 1024;              // 2048 floats
    float* ctx     = f + 3072;              // 65536 floats
    float* biasb   = f + 68608;             // 4096 floats
    ushort* u      = (ushort*)(f + 72704);
    ushort* wkv16  = u;                     // 131072
    ushort* kv16   = u + 131072;            // 4194304
    ushort* A16    = u + 4325376;           // 1048576

    // L1: zero accumulators + convert w_kv
    cvtw_kernel<<<512, 256, 0, stream>>>(w_kv, wkv16, statacc);
    // L2: kv GEMM (fused cond transpose+cvt) + GN stats, one dispatch
    kvstats_kernel<<<1536, 256, 0, stream>>>(wkv16, cond, b_kv, kv16, x, statacc);
    // L3: unnormalized context + row sums
    ctx_partial_kernel<<<dim3(8, 64), 256, 0, stream>>>(kv16, rowsum, ctx);
    // L4: fold everything into per-batch A (bf16) + bias
    a_kernel<<<256, 256, 0, stream>>>(ctx, rowsum, w_out, w_q, b_q, statacc,
                                      gn_w, gn_b, b_out, A16, biasb);
    // L5: out = A @ x^T + bias (fused x transpose+cvt in staging)
    out_gemm_fused<<<dim3(32, 16), 512, 0, stream>>>(A16, x, biasb, out);
}